// Round 1
// baseline (461.952 us; speedup 1.0000x reference)
//
#include <hip/hip_runtime.h>

// out[b,s,e] = prod_{j<=e} cos(x[b,s,j])  -- cumprod of cos along last axis.
// x: f32[16, 8192, 512] -> 131072 rows of length 512.
// One 64-lane wave per row: each lane owns 8 contiguous elements (2x float4),
// lane-local prefix products, 6-step shfl_up inclusive scan across the wave,
// then exclusive-scale + 2x float4 nontemporal store.
//
// Memory-bound: 256 MiB in + 256 MiB out = 536.9 MB -> ~85-92 us at the
// ~6.3 TB/s achievable ceiling. R1 changes vs baseline (421.9 us incl.
// harness poison fills):
//  * precise cosf -> __cosf (native v_cos_f32). Inputs ~N(0,1) so |x| <~ 6;
//    per-term abs error ~1e-6, accumulated cumprod error ~1e-4, tolerance
//    3.9e-3 -> ~30x margin. Cuts ~30 VALU instrs/element.
//  * nontemporal stores: out is write-once, never re-read; skip L2
//    write-allocate on the streaming store path.

#define ROW_LEN 512

typedef float v4f __attribute__((ext_vector_type(4)));

__global__ __launch_bounds__(256) void cumprod_cos_kernel(
    const float* __restrict__ x, float* __restrict__ out, int nrows) {
    const int wave_in_block = threadIdx.x >> 6;
    const int lane          = threadIdx.x & 63;
    const int row = blockIdx.x * (blockDim.x >> 6) + wave_in_block;
    if (row >= nrows) return;

    const size_t row_base = (size_t)row * ROW_LEN;
    // lane's chunk: elements [lane*8, lane*8+8)
    const v4f* __restrict__ xin =
        reinterpret_cast<const v4f*>(x + row_base) + lane * 2;
    v4f a = xin[0];
    v4f b = xin[1];

    // native cos (v_cos_f32, argument scaled to revolutions by the compiler)
    float c0 = __cosf(a.x), c1 = __cosf(a.y), c2 = __cosf(a.z), c3 = __cosf(a.w);
    float c4 = __cosf(b.x), c5 = __cosf(b.y), c6 = __cosf(b.z), c7 = __cosf(b.w);

    // lane-local inclusive prefix products
    float p0 = c0;
    float p1 = p0 * c1;
    float p2 = p1 * c2;
    float p3 = p2 * c3;
    float p4 = p3 * c4;
    float p5 = p4 * c5;
    float p6 = p5 * c6;
    float p7 = p6 * c7;

    // wave-wide inclusive scan (product) of lane totals, 6 shfl_up steps
    float scan = p7;
    #pragma unroll
    for (int off = 1; off < 64; off <<= 1) {
        float n = __shfl_up(scan, off, 64);
        scan *= (lane >= off) ? n : 1.0f;
    }
    // exclusive prefix for this lane
    float excl = __shfl_up(scan, 1, 64);
    if (lane == 0) excl = 1.0f;

    v4f o0 = {excl * p0, excl * p1, excl * p2, excl * p3};
    v4f o1 = {excl * p4, excl * p5, excl * p6, excl * p7};
    v4f* __restrict__ op = reinterpret_cast<v4f*>(out + row_base) + lane * 2;
    __builtin_nontemporal_store(o0, op);
    __builtin_nontemporal_store(o1, op + 1);
}

extern "C" void kernel_launch(void* const* d_in, const int* in_sizes, int n_in,
                              void* d_out, int out_size, void* d_ws, size_t ws_size,
                              hipStream_t stream) {
    const float* x = (const float*)d_in[0];
    float* out = (float*)d_out;
    const int nrows = in_sizes[0] / ROW_LEN;  // 131072
    const int waves_per_block = 4;            // 256 threads
    const int grid = (nrows + waves_per_block - 1) / waves_per_block;
    cumprod_cos_kernel<<<grid, 256, 0, stream>>>(x, out, nrows);
}

// Round 2
// 426.795 us; speedup vs baseline: 1.0824x; 1.0824x over previous
//
#include <hip/hip_runtime.h>

// out[b,s,e] = prod_{j<=e} cos(x[b,s,j])  -- cumprod of cos along last axis.
// x: f32[16, 8192, 512] -> 131072 rows of length 512.
// One 64-lane wave per row: each lane owns 8 contiguous elements (2x float4),
// lane-local prefix products, 6-step shfl_up inclusive scan across the wave,
// then exclusive-scale + 2x float4 store.
//
// Memory-bound. Ideal traffic: <=256 MiB read (R1 counters showed only 128 MiB
// fetched -- input is partially L3-resident) + 256 MiB write -> floor ~70-90 us.
// R2 = R1 minus the regression:
//  * KEEP __cosf (native v_cos_f32): VALUBusy 11%, absmax unchanged 3.9e-3 thresh
//    with ~30x margin (inputs N(0,1), per-term err ~1e-6, cumprod err ~1e-4).
//  * REVERT nontemporal stores -> plain float4 stores. R1 counters: nt stores
//    caused 19% WRITE_SIZE amplification and capped the kernel at 2.6 TB/s /
//    174 us (vs ~92 us in R0). L2 write-merging is load-bearing for streaming
//    stores on gfx950; do not bypass it.

#define ROW_LEN 512

typedef float v4f __attribute__((ext_vector_type(4)));

__global__ __launch_bounds__(256) void cumprod_cos_kernel(
    const float* __restrict__ x, float* __restrict__ out, int nrows) {
    const int wave_in_block = threadIdx.x >> 6;
    const int lane          = threadIdx.x & 63;
    const int row = blockIdx.x * (blockDim.x >> 6) + wave_in_block;
    if (row >= nrows) return;

    const size_t row_base = (size_t)row * ROW_LEN;
    // lane's chunk: elements [lane*8, lane*8+8)
    const v4f* __restrict__ xin =
        reinterpret_cast<const v4f*>(x + row_base) + lane * 2;
    v4f a = xin[0];
    v4f b = xin[1];

    // native cos (v_cos_f32; compiler emits the revolution-scaling + v_fract
    // range reduction)
    float c0 = __cosf(a.x), c1 = __cosf(a.y), c2 = __cosf(a.z), c3 = __cosf(a.w);
    float c4 = __cosf(b.x), c5 = __cosf(b.y), c6 = __cosf(b.z), c7 = __cosf(b.w);

    // lane-local inclusive prefix products
    float p0 = c0;
    float p1 = p0 * c1;
    float p2 = p1 * c2;
    float p3 = p2 * c3;
    float p4 = p3 * c4;
    float p5 = p4 * c5;
    float p6 = p5 * c6;
    float p7 = p6 * c7;

    // wave-wide inclusive scan (product) of lane totals, 6 shfl_up steps
    float scan = p7;
    #pragma unroll
    for (int off = 1; off < 64; off <<= 1) {
        float n = __shfl_up(scan, off, 64);
        scan *= (lane >= off) ? n : 1.0f;
    }
    // exclusive prefix for this lane
    float excl = __shfl_up(scan, 1, 64);
    if (lane == 0) excl = 1.0f;

    v4f o0 = {excl * p0, excl * p1, excl * p2, excl * p3};
    v4f o1 = {excl * p4, excl * p5, excl * p6, excl * p7};
    v4f* __restrict__ op = reinterpret_cast<v4f*>(out + row_base) + lane * 2;
    op[0] = o0;
    op[1] = o1;
}

extern "C" void kernel_launch(void* const* d_in, const int* in_sizes, int n_in,
                              void* d_out, int out_size, void* d_ws, size_t ws_size,
                              hipStream_t stream) {
    const float* x = (const float*)d_in[0];
    float* out = (float*)d_out;
    const int nrows = in_sizes[0] / ROW_LEN;  // 131072
    const int waves_per_block = 4;            // 256 threads
    const int grid = (nrows + waves_per_block - 1) / waves_per_block;
    cumprod_cos_kernel<<<grid, 256, 0, stream>>>(x, out, nrows);
}